// Round 4
// baseline (32.339 us; speedup 1.0000x reference)
//
#include <hip/hip_runtime.h>
#include <math.h>

#define BB 32
#define LL 512
#define DD 1024
#define TT 256
#define NK 136393      // total kept (s,e) pairs per batch
#define NK_LIN 131273  // offset(502) = 502*523/2
#define S_LIN 502
#define NEG_BIG  -3.0e38f   // finite stand-in for -inf in output
#define NEG_MASK -1.0e30f   // finite stand-in for masked logits

typedef float f4v __attribute__((ext_vector_type(4)));
typedef float f2v __attribute__((ext_vector_type(2)));

// ---------------- Kernel A: logits (+ fused flag scatter) ------------------
// One wave per row (4 rows/block). Text loads: 4x nontemporal float4/lane
// (1 KB/instr/wave, streaming). W loads: 3x float4 per j (L1-resident).
__global__ __launch_bounds__(256) void logits_kernel(
    const float* __restrict__ text, const float* __restrict__ W,
    const float* __restrict__ bias, const int* __restrict__ mask,
    const int* __restrict__ tmap,
    float* __restrict__ slp, float* __restrict__ elp, float* __restrict__ mlp,
    int* __restrict__ fs, int* __restrict__ fe)
{
    __shared__ int tsl[LL];
    __shared__ int tel[LL];
    const int wid  = threadIdx.x >> 6;
    const int lane = threadIdx.x & 63;
    const int row  = blockIdx.x * 4 + wid;        // row = b*L + l
    const int b    = blockIdx.x;                  // flag batch (blocks 0..31)
    const int t    = threadIdx.x;

    if (b < BB) {                                 // block-uniform branch
        tsl[t] = 0; tsl[t + 256] = 0;
        tel[t] = 0; tel[t + 256] = 0;
        __syncthreads();
        int s0 = tmap[((size_t)b * TT + t) * 2 + 0];
        int e0 = tmap[((size_t)b * TT + t) * 2 + 1] - 1;
        s0 = min(max(s0, 0), LL - 1);
        e0 = min(max(e0, 0), LL - 1);
        tsl[s0] = 1;                              // benign race: all write 1
        tel[e0] = 1;
        __syncthreads();
    }

    // ---- GEMV: 3 dot products of length 1024 ----
    const f4v* t4 = (const f4v*)(text + (size_t)row * DD);
    const f4v* w4 = (const f4v*)W;                // (1024,3) = 768 float4s
    float a0 = 0.f, a1 = 0.f, a2 = 0.f;
#pragma unroll
    for (int j = 0; j < 4; ++j) {
        const int fi = lane + j * 64;
        f4v v  = __builtin_nontemporal_load(&t4[fi]);
        f4v w0 = w4[fi * 3 + 0];   // {W[d0][0..2], W[d1][0]}
        f4v w1 = w4[fi * 3 + 1];   // {W[d1][1..2], W[d2][0..1]}
        f4v w2 = w4[fi * 3 + 2];   // {W[d2][2], W[d3][0..2]}
        a0 += v.x * w0.x;  a1 += v.x * w0.y;  a2 += v.x * w0.z;
        a0 += v.y * w0.w;  a1 += v.y * w1.x;  a2 += v.y * w1.y;
        a0 += v.z * w1.z;  a1 += v.z * w1.w;  a2 += v.z * w2.x;
        a0 += v.w * w2.y;  a1 += v.w * w2.z;  a2 += v.w * w2.w;
    }
#pragma unroll
    for (int off = 32; off; off >>= 1) {
        a0 += __shfl_down(a0, off);
        a1 += __shfl_down(a1, off);
        a2 += __shfl_down(a2, off);
    }
    if (lane == 0) {
        const int m = mask[row];
        slp[row] = (m == 1) ? a0 + bias[0] : NEG_MASK;
        elp[row] = (m == 1) ? a1 + bias[1] : NEG_MASK;
        mlp[row] = (m == 1) ? a2 + bias[2] : NEG_MASK;
    }

    if (b < BB) {
        const int i0 = b * LL + t, i1 = i0 + 256;
        fs[i0] = (t != 0 && mask[i0] == 1 && tsl[t]) ? 1 : 0;
        fs[i1] = (mask[i1] == 1 && tsl[t + 256]) ? 1 : 0;
        fe[i0] = (t != 0 && tel[t]) ? 1 : 0;
        fe[i1] = tel[t + 256] ? 1 : 0;
    }
}

// ---------------- Kernel B: row-based emit (scores + bounds) ---------------
// blockIdx.x = s (row), blockIdx.y = b. s and all s-indexed data are
// wave-uniform scalars; threads map to e (2 per thread). Row s holds
// e in [0, min(512, s+11)); valid pairs are the <=11 at the row's end.
__global__ __launch_bounds__(256) void out_kernel(
    const float* __restrict__ slp, const float* __restrict__ elp,
    const float* __restrict__ mlp,
    const int* __restrict__ fs, const int* __restrict__ fe,
    float* __restrict__ out)
{
    const int s = blockIdx.x;
    const int b = blockIdx.y;
    const int t = threadIdx.x;
    const int rowlen = min(LL, s + 11);
    const size_t obase = (size_t)b * NK +
        (s <= S_LIN ? s * (s + 21) / 2 : NK_LIN + (s - S_LIN) * LL);
    const int base = b * LL;
    const int   fss = fs[base + s];     // uniform -> scalar load
    const float sv  = slp[base + s];    // uniform
    f2v* bptr = (f2v*)(out + (size_t)BB * NK);

#pragma unroll
    for (int h = 0; h < 2; ++h) {
        const int e = t + h * 256;
        if (e < rowlen) {
            float score = NEG_BIG;
            if (e >= s && fss && fe[base + e]) {
                float w = 0.f;
                for (int l = s; l <= e; ++l) w += mlp[base + l];  // <=11, L1-hot
                score = (sv + elp[base + e]) + w;
            }
            __builtin_nontemporal_store(score, &out[obase + e]);
            f2v bv; bv.x = (float)s; bv.y = (float)e;
            __builtin_nontemporal_store(bv, &bptr[obase + e]);
        }
    }
}

extern "C" void kernel_launch(void* const* d_in, const int* in_sizes, int n_in,
                              void* d_out, int out_size, void* d_ws, size_t ws_size,
                              hipStream_t stream) {
    const float* text = (const float*)d_in[0];   // (B,L,D) f32
    const int*   mask = (const int*)d_in[1];     // (B,L) i32
    const int*   tmap = (const int*)d_in[2];     // (B,T,2) i32
    const float* W    = (const float*)d_in[3];   // (D,3) f32
    const float* bias = (const float*)d_in[4];   // (3,) f32
    float* out = (float*)d_out;

    float* slp = (float*)d_ws;                   // B*L each
    float* elp = slp + (size_t)BB * LL;
    float* mlp = elp + (size_t)BB * LL;
    int*   fs  = (int*)(mlp + (size_t)BB * LL);
    int*   fe  = fs + (size_t)BB * LL;

    logits_kernel<<<BB * LL / 4, 256, 0, stream>>>(text, W, bias, mask, tmap,
                                                   slp, elp, mlp, fs, fe);
    dim3 g2(LL, BB);
    out_kernel<<<g2, 256, 0, stream>>>(slp, elp, mlp, fs, fe, out);
}